// Round 3
// baseline (27.781 us; speedup 1.0000x reference)
//
#include <hip/hip_runtime.h>
#include <math.h>

// B=64, M=8, K=4, P=16, V=65536.
// Grid 1024 = 64 batches x 16 chunks (chunk = digit0), 256 threads.
// Thread t owns column (d2 = t>>4, d3 = t&15); s-loop covers d1 = 0..15.
// 16-lane "cluster" = threads sharing t>>4 (lane-contiguous within a wave).
// Groups g = j*16+p; j0 finalized in-block; j1..j3 emit (max, sum) pairs
// per chunk to ws; k_comb LSE-merges the 16 chunks per group.

__global__ __launch_bounds__(256) void k_main(
    const float* __restrict__ yr, const float* __restrict__ yi,
    const float* __restrict__ hr, const float* __restrict__ hi,
    const float* __restrict__ sr, const float* __restrict__ si,
    const float* __restrict__ vr, const float* __restrict__ vi,
    float* __restrict__ ws, float* __restrict__ out)
{
    __shared__ float sL[8][8][2];     // Cholesky rows
    __shared__ float sDinv[8];
    __shared__ float lyw[8][2];
    __shared__ float lhw[8][4][2];    // whitened h [m][k]
    __shared__ float tab[4][8][16][2]; // [k][m][p]: hw[m][k]*pts[p]
    __shared__ float pn2b[16];        // |pts[p]|^2
    __shared__ float Hn1b;            // sum_m |hw[m][1]|^2
    __shared__ float m3w[4][16], s3w[4][16];
    __shared__ float p1buf[16][16];   // [s][cluster] partial sums (norm: m1cbuf)
    __shared__ float m1cbuf[16][16];  // [s][cluster] row-cluster maxes
    __shared__ float m2buf[16], s2buf[16];

    const int t = threadIdx.x;
    const int b = blockIdx.x >> 4, chunk = blockIdx.x & 15;
    const int lane = t & 63, wv = t >> 6;
    const int i3 = t & 15, i2 = t >> 4;

    // ================= wave 0: whiten + tables =================
    if (wv == 0) {
        float ar_[8] = {}, ai_[8] = {}, Lr_[8] = {}, Li_[8] = {};
        if (lane < 8) {
#pragma unroll
            for (int k = 0; k < 8; ++k) {
                ar_[k] = sr[b * 64 + lane * 8 + k];
                ai_[k] = si[b * 64 + lane * 8 + k];
            }
        }
        float inv = 0.f;
#pragma unroll
        for (int j = 0; j < 8; ++j) {
            if (lane == j) {
                float d = ar_[j];
#pragma unroll
                for (int k = 0; k < 8; ++k) if (k < j) d -= Lr_[k]*Lr_[k] + Li_[k]*Li_[k];
                float ld = sqrtf(d);
                Lr_[j] = ld; Li_[j] = 0.f;
                inv = 1.f / ld;
                sDinv[j] = inv;
            }
            float invj = __shfl(inv, j);
            float cr = ar_[j], ci = ai_[j];
#pragma unroll
            for (int k = 0; k < 8; ++k) if (k < j) {
                float Ljrk = __shfl(Lr_[k], j);
                float Ljik = __shfl(Li_[k], j);
                cr -= Lr_[k]*Ljrk + Li_[k]*Ljik;
                ci -= Li_[k]*Ljrk - Lr_[k]*Ljik;
            }
            if (lane < 8 && lane > j) { Lr_[j] = cr * invj; Li_[j] = ci * invj; }
        }
        if (lane < 8) {
#pragma unroll
            for (int k = 0; k < 8; ++k) if (k <= lane) { sL[lane][k][0] = Lr_[k]; sL[lane][k][1] = Li_[k]; }
        }
        // 5 forward solves: lane 0 -> y, lanes 1..4 -> h columns
        if (lane < 5) {
            float rr[8], ri[8], zr[8], zi[8];
            if (lane == 0) {
#pragma unroll
                for (int i = 0; i < 8; ++i) { rr[i] = yr[b*8+i]; ri[i] = yi[b*8+i]; }
            } else {
#pragma unroll
                for (int i = 0; i < 8; ++i) { rr[i] = hr[(b*8+i)*4 + (lane-1)]; ri[i] = hi[(b*8+i)*4 + (lane-1)]; }
            }
#pragma unroll
            for (int i = 0; i < 8; ++i) {
                float cr = rr[i], ci = ri[i];
#pragma unroll
                for (int k = 0; k < 8; ++k) if (k < i) {
                    cr -= sL[i][k][0]*zr[k] - sL[i][k][1]*zi[k];
                    ci -= sL[i][k][0]*zi[k] + sL[i][k][1]*zr[k];
                }
                float dv = sDinv[i];
                zr[i] = cr * dv; zi[i] = ci * dv;
                if (lane == 0) { lyw[i][0] = zr[i]; lyw[i][1] = zi[i]; }
                else           { lhw[i][lane-1][0] = zr[i]; lhw[i][lane-1][1] = zi[i]; }
            }
        }
        // tab build (reads lhw written by this wave; compiler orders LDS)
        {
            int p = lane & 15;
            float pr  = vr[(p << 12) * 4];
            float pim = vi[(p << 12) * 4];
            if (lane < 16) pn2b[lane] = pr*pr + pim*pim;
            if (lane == 0) {
                float hn = 0.f;
#pragma unroll
                for (int m = 0; m < 8; ++m) hn += lhw[m][1][0]*lhw[m][1][0] + lhw[m][1][1]*lhw[m][1][1];
                Hn1b = hn;
            }
#pragma unroll
            for (int it = 0; it < 8; ++it) {
                int e = lane + it * 64;
                int k = e >> 7, m = (e >> 4) & 7;
                float hre = lhw[m][k][0], him = lhw[m][k][1];
                tab[k][m][p][0] = hre*pr  - him*pim;
                tab[k][m][p][1] = hre*pim + him*pr;
            }
        }
    }
    __syncthreads();   // #1

    // ================= per-thread base vector + |b|^2 =================
    float br_[8], bi_[8];
    float B2 = 0.f;
#pragma unroll
    for (int m = 0; m < 8; ++m) {
        const float2 t0 = *(const float2*)&tab[0][m][chunk][0];
        const float2 t2 = *(const float2*)&tab[2][m][i2][0];
        const float2 t3 = *(const float2*)&tab[3][m][i3][0];
        const float2 yw = *(const float2*)&lyw[m][0];
        br_[m] = t0.x + t2.x + t3.x - yw.x;
        bi_[m] = t0.y + t2.y + t3.y - yw.y;
        B2 = fmaf(br_[m], br_[m], fmaf(bi_[m], bi_[m], B2));
    }
    const float Hn1 = Hn1b;

    // ================= x for 16 candidates (expansion) =================
    float x_[16];
    float vmA = -3.4e38f;
#pragma unroll
    for (int s = 0; s < 16; ++s) {
        float D = 0.f;
#pragma unroll
        for (int m = 0; m < 8; ++m) {
            const float2 t1 = *(const float2*)&tab[1][m][s][0];
            D = fmaf(br_[m], t1.x, D);
            D = fmaf(bi_[m], t1.y, D);
        }
        float x = fmaf(-2.f, D, -fmaf(pn2b[s], Hn1, B2));
        x_[s] = x;
        vmA = fmaxf(vmA, x);
    }

    // M2 = cluster max (j2 group i2); M3 wave-partial
    float M2 = vmA;
    M2 = fmaxf(M2, __shfl_xor(M2, 1));
    M2 = fmaxf(M2, __shfl_xor(M2, 2));
    M2 = fmaxf(M2, __shfl_xor(M2, 4));
    M2 = fmaxf(M2, __shfl_xor(M2, 8));
    float m3p = vmA;
    m3p = fmaxf(m3p, __shfl_xor(m3p, 16));
    m3p = fmaxf(m3p, __shfl_xor(m3p, 32));
    if (lane < 16) m3w[wv][lane] = m3p;

    // j1: per-(row s, cluster) max + normalized partial sum (no barrier needed yet)
#pragma unroll
    for (int s = 0; s < 16; ++s) {
        float rcm = x_[s];
        rcm = fmaxf(rcm, __shfl_xor(rcm, 1));
        rcm = fmaxf(rcm, __shfl_xor(rcm, 2));
        rcm = fmaxf(rcm, __shfl_xor(rcm, 4));
        rcm = fmaxf(rcm, __shfl_xor(rcm, 8));
        float e1 = __expf(x_[s] - rcm);
        e1 += __shfl_xor(e1, 1);
        e1 += __shfl_xor(e1, 2);
        e1 += __shfl_xor(e1, 4);
        e1 += __shfl_xor(e1, 8);
        if (i3 == 0) { p1buf[s][i2] = e1; m1cbuf[s][i2] = rcm; }
    }
    __syncthreads();   // #2

    // j2/j3 sums with shared normalization Mlo = min(M2, M3) (both >= vmA)
    const float M3 = fmaxf(fmaxf(m3w[0][i3], m3w[1][i3]), fmaxf(m3w[2][i3], m3w[3][i3]));
    const float Mlo = fminf(M2, M3);
    float acc = 0.f;
#pragma unroll
    for (int s = 0; s < 16; ++s) acc += __expf(x_[s] - Mlo);
    float acc2 = acc * __expf(Mlo - M2);   // factor <= 1
    float acc3 = acc * __expf(Mlo - M3);   // factor <= 1
    float S2 = acc2;
    S2 += __shfl_xor(S2, 1);
    S2 += __shfl_xor(S2, 2);
    S2 += __shfl_xor(S2, 4);
    S2 += __shfl_xor(S2, 8);
    float s3p = acc3;
    s3p += __shfl_xor(s3p, 16);
    s3p += __shfl_xor(s3p, 32);
    if (lane < 16) s3w[wv][lane] = s3p;
    if (i3 == 0) {
        m2buf[i2] = M2; s2buf[i2] = S2;
        float* w = ws + ((b*48 + 16 + i2)*16 + chunk)*2;
        w[0] = M2; w[1] = S2;
    }
    __syncthreads();   // #3

    // j1 finalize: thread t -> (row s = t>>4, cluster c = t&15); merge 16 clusters
    {
        float p1v = p1buf[i2][i3];
        float m1c = m1cbuf[i2][i3];
        float M1 = m1c;
        M1 = fmaxf(M1, __shfl_xor(M1, 1));
        M1 = fmaxf(M1, __shfl_xor(M1, 2));
        M1 = fmaxf(M1, __shfl_xor(M1, 4));
        M1 = fmaxf(M1, __shfl_xor(M1, 8));
        float q = p1v * __expf(m1c - M1);   // factor <= 1, p1v in [1,16]
        q += __shfl_xor(q, 1);
        q += __shfl_xor(q, 2);
        q += __shfl_xor(q, 4);
        q += __shfl_xor(q, 8);
        if (i3 == 0) {
            float* w = ws + ((b*48 + i2)*16 + chunk)*2;
            w[0] = M1; w[1] = q;
        }
    }
    // j3 finalize
    if (t < 16) {
        float S3 = s3w[0][t] + s3w[1][t] + s3w[2][t] + s3w[3][t];
        float* w = ws + ((b*48 + 32 + t)*16 + chunk)*2;
        w[0] = M3; w[1] = S3;   // thread t<16 has i3 == t, so M3 is group t's max
    }
    // j0 finalize (whole block == one j0 group)
    if (t == 0) {
        float M0 = m2buf[0];
#pragma unroll
        for (int i = 1; i < 16; ++i) M0 = fmaxf(M0, m2buf[i]);
        float S0 = 0.f;
#pragma unroll
        for (int i = 0; i < 16; ++i) S0 += s2buf[i] * __expf(m2buf[i] - M0);
        out[b*64 + chunk] = __logf(S0) + M0;
    }
}

// ---------- merge the 16 chunk-local (m,s) pairs per group ----------
__global__ __launch_bounds__(256) void k_comb(const float* __restrict__ ws, float* __restrict__ out)
{
    int idx = blockIdx.x * 256 + threadIdx.x;
    if (idx >= 64 * 48) return;
    int b = idx / 48, gi = idx % 48;
    const float* p = ws + (b*48 + gi)*32;
    float M = p[0];
#pragma unroll
    for (int i = 1; i < 16; ++i) M = fmaxf(M, p[2*i]);
    float S = 0.f;
#pragma unroll
    for (int i = 0; i < 16; ++i) S += p[2*i+1] * __expf(p[2*i] - M);
    out[b*64 + 16 + gi] = __logf(S) + M;
}

extern "C" void kernel_launch(void* const* d_in, const int* in_sizes, int n_in,
                              void* d_out, int out_size, void* d_ws, size_t ws_size,
                              hipStream_t stream) {
    const float* yr = (const float*)d_in[0];
    const float* yi = (const float*)d_in[1];
    const float* hr = (const float*)d_in[2];
    const float* hi = (const float*)d_in[3];
    const float* sr = (const float*)d_in[4];
    const float* si = (const float*)d_in[5];
    const float* vr = (const float*)d_in[6];
    const float* vi = (const float*)d_in[7];
    float* ws = (float*)d_ws;
    float* out = (float*)d_out;
    hipLaunchKernelGGL(k_main, dim3(1024), dim3(256), 0, stream,
                       yr, yi, hr, hi, sr, si, vr, vi, ws, out);
    hipLaunchKernelGGL(k_comb, dim3(12), dim3(256), 0, stream, ws, out);
}

// Round 4
// 19.706 us; speedup vs baseline: 1.4098x; 1.4098x over previous
//
#include <hip/hip_runtime.h>
#include <math.h>

// B=64, M=8, K=4, P=16, V=65536.
// Grid 1024 = 64 batches x 16 chunks (chunk = digit0), 256 threads.
// Thread t owns column (d2 = t>>4, d3 = t&15); s-loop covers d1 = 0..15.
// x computed via quadratic expansion: x = -(B2 + 2*Re<b,t1[s]> + |pts[s]|^2*Hn1).
// Reductions: LDS arrays with independent (pipelined) reads; no shfl chains.
// j0 finalized in-block; j1..j3 emit (max,sum) per chunk to ws; k_comb merges.

__global__ __launch_bounds__(256) void k_main(
    const float* __restrict__ yr, const float* __restrict__ yi,
    const float* __restrict__ hr, const float* __restrict__ hi,
    const float* __restrict__ sr, const float* __restrict__ si,
    const float* __restrict__ vr, const float* __restrict__ vi,
    float* __restrict__ ws, float* __restrict__ out)
{
    __shared__ float sL[8][8][2];      // Cholesky rows
    __shared__ float sDinv[8];
    __shared__ float lyw[8][2];
    __shared__ float lhw[8][4][2];     // whitened h [m][k]
    __shared__ float tab[4][8][16][2]; // [k][m][p]: hw[m][k]*pts[p]
    __shared__ float pn2b[16];         // |pts[p]|^2
    __shared__ float Hn1b;             // sum_m |hw[m][1]|^2
    __shared__ float xbuf[16][256];    // x values [d1=s][t]
    __shared__ float pmax[256];        // per-thread max over s
    __shared__ float cm[16][17];       // [s][cluster] maxes, then reused for j1 sums
    __shared__ float m1buf[16], m2buf[16], m3buf[16];
    __shared__ float part2[256], part3[256];
    __shared__ float s2buf[16];

    const int t = threadIdx.x;
    const int b = blockIdx.x >> 4, chunk = blockIdx.x & 15;
    const int lane = t & 63, wv = t >> 6;
    const int i3 = t & 15, i2 = t >> 4;

    // ================= wave 0: whiten + tables (validated in R2) =================
    if (wv == 0) {
        float ar_[8] = {}, ai_[8] = {}, Lr_[8] = {}, Li_[8] = {};
        if (lane < 8) {
#pragma unroll
            for (int k = 0; k < 8; ++k) {
                ar_[k] = sr[b * 64 + lane * 8 + k];
                ai_[k] = si[b * 64 + lane * 8 + k];
            }
        }
        float inv = 0.f;
#pragma unroll
        for (int j = 0; j < 8; ++j) {
            if (lane == j) {
                float d = ar_[j];
#pragma unroll
                for (int k = 0; k < 8; ++k) if (k < j) d -= Lr_[k]*Lr_[k] + Li_[k]*Li_[k];
                float ld = sqrtf(d);
                Lr_[j] = ld; Li_[j] = 0.f;
                inv = 1.f / ld;
                sDinv[j] = inv;
            }
            float invj = __shfl(inv, j);
            float cr = ar_[j], ci = ai_[j];
#pragma unroll
            for (int k = 0; k < 8; ++k) if (k < j) {
                float Ljrk = __shfl(Lr_[k], j);
                float Ljik = __shfl(Li_[k], j);
                cr -= Lr_[k]*Ljrk + Li_[k]*Ljik;
                ci -= Li_[k]*Ljrk - Lr_[k]*Ljik;
            }
            if (lane < 8 && lane > j) { Lr_[j] = cr * invj; Li_[j] = ci * invj; }
        }
        if (lane < 8) {
#pragma unroll
            for (int k = 0; k < 8; ++k) if (k <= lane) { sL[lane][k][0] = Lr_[k]; sL[lane][k][1] = Li_[k]; }
        }
        // 5 forward solves: lane 0 -> y, lanes 1..4 -> h columns
        if (lane < 5) {
            float rr[8], ri[8], zr[8], zi[8];
            if (lane == 0) {
#pragma unroll
                for (int i = 0; i < 8; ++i) { rr[i] = yr[b*8+i]; ri[i] = yi[b*8+i]; }
            } else {
#pragma unroll
                for (int i = 0; i < 8; ++i) { rr[i] = hr[(b*8+i)*4 + (lane-1)]; ri[i] = hi[(b*8+i)*4 + (lane-1)]; }
            }
#pragma unroll
            for (int i = 0; i < 8; ++i) {
                float cr = rr[i], ci = ri[i];
#pragma unroll
                for (int k = 0; k < 8; ++k) if (k < i) {
                    cr -= sL[i][k][0]*zr[k] - sL[i][k][1]*zi[k];
                    ci -= sL[i][k][0]*zi[k] + sL[i][k][1]*zr[k];
                }
                float dv = sDinv[i];
                zr[i] = cr * dv; zi[i] = ci * dv;
                if (lane == 0) { lyw[i][0] = zr[i]; lyw[i][1] = zi[i]; }
                else           { lhw[i][lane-1][0] = zr[i]; lhw[i][lane-1][1] = zi[i]; }
            }
        }
        {
            int p = lane & 15;
            float pr  = vr[(p << 12) * 4];
            float pim = vi[(p << 12) * 4];
            if (lane < 16) pn2b[lane] = pr*pr + pim*pim;
            if (lane == 0) {
                float hn = 0.f;
#pragma unroll
                for (int m = 0; m < 8; ++m) hn += lhw[m][1][0]*lhw[m][1][0] + lhw[m][1][1]*lhw[m][1][1];
                Hn1b = hn;
            }
#pragma unroll
            for (int it = 0; it < 8; ++it) {
                int e = lane + it * 64;
                int k = e >> 7, m = (e >> 4) & 7;
                float hre = lhw[m][k][0], him = lhw[m][k][1];
                tab[k][m][p][0] = hre*pr  - him*pim;
                tab[k][m][p][1] = hre*pim + him*pr;
            }
        }
    }
    __syncthreads();   // A

    // ================= phase 1: x via expansion =================
    float br_[8], bi_[8];
    float B2 = 0.f;
#pragma unroll
    for (int m = 0; m < 8; ++m) {
        const float2 t0 = *(const float2*)&tab[0][m][chunk][0];
        const float2 t2 = *(const float2*)&tab[2][m][i2][0];
        const float2 t3 = *(const float2*)&tab[3][m][i3][0];
        const float2 yw = *(const float2*)&lyw[m][0];
        br_[m] = t0.x + t2.x + t3.x - yw.x;
        bi_[m] = t0.y + t2.y + t3.y - yw.y;
        B2 = fmaf(br_[m], br_[m], fmaf(bi_[m], bi_[m], B2));
    }
    const float Hn1 = Hn1b;

    float x_[16];
    float vmA = -3.4e38f;
#pragma unroll
    for (int s = 0; s < 16; ++s) {
        float D = 0.f;
#pragma unroll
        for (int m = 0; m < 8; ++m) {
            const float2 t1 = *(const float2*)&tab[1][m][s][0];
            D = fmaf(br_[m], t1.x, D);
            D = fmaf(bi_[m], t1.y, D);
        }
        float x = fmaf(-2.f, D, -fmaf(pn2b[s], Hn1, B2));
        x_[s] = x;
        vmA = fmaxf(vmA, x);
        xbuf[s][t] = x;              // stride-1 across lanes: conflict-free
    }
    pmax[t] = vmA;
    __syncthreads();   // B

    // ================= phase 2a: cluster maxes for j1; M2/M3 =================
    // role: su = t&15 (row s), seg = t>>4 (cluster). Rotated reads -> 2-way (free).
    const int su = i3, seg = i2;
    {
        float m = -3.4e38f;
#pragma unroll
        for (int j = 0; j < 16; ++j) m = fmaxf(m, xbuf[su][seg*16 + ((j + su) & 15)]);
        cm[su][seg] = m;
    }
    if (t < 16) {                       // M2 for cluster t (16 reads, 8-way on 16 lanes)
        float m = -3.4e38f;
#pragma unroll
        for (int j = 0; j < 16; ++j) m = fmaxf(m, pmax[t*16 + j]);
        m2buf[t] = m;
    } else if (t < 32) {                // M3 for d3 = t-16
        int d = t - 16;
        float m = -3.4e38f;
#pragma unroll
        for (int j = 0; j < 16; ++j) m = fmaxf(m, pmax[d + 16*j]);
        m3buf[d] = m;
    }
    __syncthreads();   // C

    // ================= phase 2b: M1; j2/j3 partials via shared exps =================
    if (t < 16) {
        float m = -3.4e38f;
#pragma unroll
        for (int j = 0; j < 16; ++j) m = fmaxf(m, cm[t][j]);
        m1buf[t] = m;
    }
    const float M2 = m2buf[i2], M3 = m3buf[i3];
    const float Mlo = fminf(M2, M3);
    float acc = 0.f;
#pragma unroll
    for (int s = 0; s < 16; ++s) acc += __expf(x_[s] - Mlo);
    part2[t] = acc * __expf(Mlo - M2);   // == sum_s exp(x_s - M2), factor <= 1
    part3[t] = acc * __expf(Mlo - M3);
    __syncthreads();   // D

    // ================= phase 2c: j1 exp-sums; j2/j3 group sums =================
    {
        const float M1 = m1buf[su];
        float ssum = 0.f;
#pragma unroll
        for (int j = 0; j < 16; ++j)
            ssum += __expf(xbuf[su][seg*16 + ((j + su) & 15)] - M1);
        cm[su][seg] = ssum;              // reuse cm as j1 partial-sum buffer
    }
    if (t < 16) {
        float S2 = 0.f;
#pragma unroll
        for (int j = 0; j < 16; ++j) S2 += part2[t*16 + j];
        s2buf[t] = S2;
        float* w = ws + ((b*48 + 16 + t)*16 + chunk)*2;
        w[0] = m2buf[t]; w[1] = S2;
    } else if (t < 32) {
        int d = t - 16;
        float S3 = 0.f;
#pragma unroll
        for (int j = 0; j < 16; ++j) S3 += part3[d + 16*j];
        float* w = ws + ((b*48 + 32 + d)*16 + chunk)*2;
        w[0] = m3buf[d]; w[1] = S3;
    }
    __syncthreads();   // E

    // ================= phase 3: j1 finalize + j0 =================
    if (t < 16) {
        float S1 = 0.f;
#pragma unroll
        for (int j = 0; j < 16; ++j) S1 += cm[t][j];
        float* w = ws + ((b*48 + t)*16 + chunk)*2;
        w[0] = m1buf[t]; w[1] = S1;
    }
    if (t == 16) {   // j0: exact LSE-merge of the 16 (M2,S2) cluster pairs
        float M0 = m2buf[0];
#pragma unroll
        for (int i = 1; i < 16; ++i) M0 = fmaxf(M0, m2buf[i]);
        float S0 = 0.f;
#pragma unroll
        for (int i = 0; i < 16; ++i) S0 += s2buf[i] * __expf(m2buf[i] - M0);
        out[b*64 + chunk] = __logf(S0) + M0;
    }
}

// ---------- merge the 16 chunk-local (max,sum) pairs per group ----------
__global__ __launch_bounds__(256) void k_comb(const float* __restrict__ ws, float* __restrict__ out)
{
    int idx = blockIdx.x * 256 + threadIdx.x;
    if (idx >= 64 * 48) return;
    int b = idx / 48, gi = idx % 48;
    const float* p = ws + (b*48 + gi)*32;
    float M = p[0];
#pragma unroll
    for (int i = 1; i < 16; ++i) M = fmaxf(M, p[2*i]);
    float S = 0.f;
#pragma unroll
    for (int i = 0; i < 16; ++i) S += p[2*i+1] * __expf(p[2*i] - M);
    out[b*64 + 16 + gi] = __logf(S) + M;
}

extern "C" void kernel_launch(void* const* d_in, const int* in_sizes, int n_in,
                              void* d_out, int out_size, void* d_ws, size_t ws_size,
                              hipStream_t stream) {
    const float* yr = (const float*)d_in[0];
    const float* yi = (const float*)d_in[1];
    const float* hr = (const float*)d_in[2];
    const float* hi = (const float*)d_in[3];
    const float* sr = (const float*)d_in[4];
    const float* si = (const float*)d_in[5];
    const float* vr = (const float*)d_in[6];
    const float* vi = (const float*)d_in[7];
    float* ws = (float*)d_ws;
    float* out = (float*)d_out;
    hipLaunchKernelGGL(k_main, dim3(1024), dim3(256), 0, stream,
                       yr, yi, hr, hi, sr, si, vr, vi, ws, out);
    hipLaunchKernelGGL(k_comb, dim3(12), dim3(256), 0, stream, ws, out);
}